// Round 6
// baseline (368.792 us; speedup 1.0000x reference)
//
#include <hip/hip_runtime.h>

typedef __bf16 bf16;
typedef __bf16 bf16x8 __attribute__((ext_vector_type(8)));
typedef __bf16 bf16x4 __attribute__((ext_vector_type(4)));
typedef float  f32x4  __attribute__((ext_vector_type(4)));

#define CDIM   512
#define NPOS   1024
#define NBATCH 16
#define MTOT   (NBATCH * NPOS)
#define WELEMS (CDIM * CDIM)

// ---------------- workspace layout (bytes) ----------------
#define OFF_WT  ((size_t)0)
#define OFF_XN  ((size_t)(2 * 1024 * 1024))
#define OFF_Q   (OFF_XN + (size_t)MTOT * CDIM * 2)
#define OFF_K   (OFF_Q  + (size_t)MTOT * CDIM * 2)
#define OFF_VT  (OFF_K  + (size_t)MTOT * CDIM * 2)
#define OFF_O   OFF_XN   // xn dead after QKV GEMM; reuse for O

// async global->LDS, 16B per lane. LDS dest must be wave-uniform base + lane*16.
__device__ __forceinline__ void gload16(const bf16* g, bf16* l) {
    __builtin_amdgcn_global_load_lds(
        (const __attribute__((address_space(1))) void*)g,
        (__attribute__((address_space(3))) void*)l, 16, 0, 0);
}

__device__ __forceinline__ unsigned int pk2(float lo, float hi) {
    union { bf16 h; unsigned short s; } a, c;
    a.h = (bf16)lo; c.h = (bf16)hi;
    return (unsigned int)a.s | ((unsigned int)c.s << 16);
}

// ---------------- weight transpose + cast ----------------
__global__ __launch_bounds__(256) void transpose_cast(
    const float* __restrict__ w0, const float* __restrict__ w1,
    const float* __restrict__ w2, const float* __restrict__ w3,
    bf16* __restrict__ wt)
{
    __shared__ bf16 tile[32][33];
    int z = blockIdx.z;
    const float* W = (z == 0) ? w0 : (z == 1) ? w1 : (z == 2) ? w2 : w3;
    bf16* out = wt + (size_t)z * WELEMS;
    int bx = blockIdx.x * 32;
    int by = blockIdx.y * 32;
    int tx = threadIdx.x & 31, ty = threadIdx.x >> 5;
    #pragma unroll
    for (int i = ty; i < 32; i += 8)
        tile[i][tx] = (bf16)W[(size_t)(by + i) * CDIM + bx + tx];
    __syncthreads();
    #pragma unroll
    for (int i = ty; i < 32; i += 8)
        out[(size_t)(bx + i) * CDIM + by + tx] = tile[tx][i];
}

// ---------------- GroupNorm -> bf16 ----------------
__global__ __launch_bounds__(256) void groupnorm_kernel(
    const float* __restrict__ x, const float* __restrict__ gamma,
    const float* __restrict__ beta, bf16* __restrict__ xn)
{
    int b = blockIdx.x >> 5;
    int g = blockIdx.x & 31;
    const float* xb = x + (size_t)b * NPOS * CDIM;
    int t = threadIdx.x, lane = t & 63, wid = t >> 6;

    float s = 0.f, s2 = 0.f;
    for (int i = t; i < 4096; i += 256) {
        int n = i >> 2, c4 = i & 3;
        const float4 v = *(const float4*)&xb[n * CDIM + g * 16 + c4 * 4];
        s  += v.x + v.y + v.z + v.w;
        s2 += v.x * v.x + v.y * v.y + v.z * v.z + v.w * v.w;
    }
    #pragma unroll
    for (int o = 32; o; o >>= 1) { s += __shfl_xor(s, o); s2 += __shfl_xor(s2, o); }
    __shared__ float rs[4], rs2[4];
    if (lane == 0) { rs[wid] = s; rs2[wid] = s2; }
    __syncthreads();
    float S  = rs[0] + rs[1] + rs[2] + rs[3];
    float S2 = rs2[0] + rs2[1] + rs2[2] + rs2[3];
    const float inv_n = 1.f / 16384.f;
    float mean = S * inv_n;
    float var  = S2 * inv_n - mean * mean;
    float rstd = rsqrtf(var + 1e-3f);

    bf16* xnb = xn + (size_t)b * NPOS * CDIM;
    for (int i = t; i < 4096; i += 256) {
        int n = i >> 2, c4 = i & 3;
        int c = g * 16 + c4 * 4;
        const float4 v = *(const float4*)&xb[n * CDIM + c];
        bf16x4 o;
        o[0] = (bf16)(((v.x - mean) * rstd) * gamma[c + 0] + beta[c + 0]);
        o[1] = (bf16)(((v.y - mean) * rstd) * gamma[c + 1] + beta[c + 1]);
        o[2] = (bf16)(((v.z - mean) * rstd) * gamma[c + 2] + beta[c + 2]);
        o[3] = (bf16)(((v.w - mean) * rstd) * gamma[c + 3] + beta[c + 3]);
        *(bf16x4*)&xnb[n * CDIM + c] = o;
    }
}

// ---------------- fused QKV GEMM: [16384,512] x [512,1536] ----------------
// XCD-chunked mapping: each XCD owns 16 row-panels x 12 col-tiles, so the 12
// col-tiles sharing an A-panel are co-resident and B (1.5MB) stays L2-resident.
#define BM 128
#define BN 128
#define BK 32

__global__ __launch_bounds__(256) void gemm_qkv(
    const bf16* __restrict__ A, const bf16* __restrict__ Bw,
    const float* __restrict__ bq, const float* __restrict__ bk,
    const float* __restrict__ bv, float qscale,
    bf16* __restrict__ Qo, bf16* __restrict__ Ko, bf16* __restrict__ Vto)
{
    __shared__ __align__(16) bf16 lsa[BM * BK];
    __shared__ __align__(16) bf16 lsb[BN * BK];
    const int bid = blockIdx.x;
    const int xcd = bid & 7;
    const int local = bid >> 3;               // 0..191
    const int colT = local % 12;
    const int rowT = (xcd << 4) + local / 12; // 0..127
    const int bm = rowT * BM;
    const int bnG = colT * BN;
    const int region = colT >> 2;             // 0=Q 1=K 2=V
    const int t = threadIdx.x;
    const int lane = t & 63;
    const int wid = t >> 6;
    const int wr = (wid >> 1) * 64;
    const int wc = (wid & 1) * 64;
    const int lr = lane & 15;
    const int ks = lane >> 4;

    const int r0 = t >> 2, c0 = (t & 3) * 8;
    const int r1 = (t + 256) >> 2, c1 = ((t + 256) & 3) * 8;

    f32x4 acc[4][4] = {};

    for (int k0 = 0; k0 < CDIM; k0 += BK) {
        gload16(&A[(size_t)(bm + r0) * CDIM + k0 + c0], &lsa[t * 8]);
        gload16(&A[(size_t)(bm + r1) * CDIM + k0 + c1], &lsa[(t + 256) * 8]);
        gload16(&Bw[(size_t)(bnG + r0) * CDIM + k0 + c0], &lsb[t * 8]);
        gload16(&Bw[(size_t)(bnG + r1) * CDIM + k0 + c1], &lsb[(t + 256) * 8]);
        __syncthreads();
        bf16x8 af[4], bfr[4];
        #pragma unroll
        for (int m = 0; m < 4; m++)
            af[m] = *(const bf16x8*)&lsa[(wr + m * 16 + lr) * BK + ks * 8];
        #pragma unroll
        for (int n = 0; n < 4; n++)
            bfr[n] = *(const bf16x8*)&lsb[(wc + n * 16 + lr) * BK + ks * 8];
        #pragma unroll
        for (int m = 0; m < 4; m++)
            #pragma unroll
            for (int n = 0; n < 4; n++)
                acc[m][n] = __builtin_amdgcn_mfma_f32_16x16x32_bf16(af[m], bfr[n], acc[m][n], 0, 0, 0);
        __syncthreads();
    }

    const float* bias = (region == 0) ? bq : (region == 1) ? bk : bv;
    const float scale = (region == 0) ? qscale : 1.f;
    #pragma unroll
    for (int m = 0; m < 4; m++) {
        #pragma unroll
        for (int n = 0; n < 4; n++) {
            const int row0 = bm + wr + m * 16 + ks * 4;
            const int colG = bnG + wc + n * 16 + lr;
            const int cl = colG - region * CDIM;
            const float bvl = bias[cl];
            #pragma unroll
            for (int r = 0; r < 4; r++) {
                const int rr = row0 + r;
                const float v = (acc[m][n][r] + bvl) * scale;
                if (region == 0) {
                    Qo[(size_t)rr * CDIM + cl] = (bf16)v;
                } else if (region == 1) {
                    Ko[(size_t)rr * CDIM + cl] = (bf16)v;
                } else {
                    const int bb = rr >> 10, nn = rr & 1023;
                    Vto[(size_t)bb * CDIM * NPOS + (size_t)cl * NPOS + nn] = (bf16)v;
                }
            }
        }
    }
}

// ---------------- flash attention (8 waves, 2/SIMD) ----------------
// 256 blocks (16b x 16 q-tiles of 64 rows), 512 threads = 4 wq x 2 wd waves.
// QK^T kv-split by wd (no redundant MFMA); softmax halves exchange per-row
// max/sum via 1KB LDS; PV d-split by wd, V read direct from global to regs.
// K double-buffered in LDS via swizzled-source global_load_lds: 2 barriers/kt.
// NOTE: plain __launch_bounds__(512) -> VGPR cap 256 (8 waves/block forces
// 2 waves/SIMD residency); the (512,2) variant capped VGPR at 128 and spilled.
#define QT 64
#define KVB 32

__global__ __launch_bounds__(512) void flash_attn(
    const bf16* __restrict__ Q, const bf16* __restrict__ K,
    const bf16* __restrict__ Vt, bf16* __restrict__ O)
{
    __shared__ __align__(16) bf16 Klds[2][KVB * CDIM];   // 64 KB
    __shared__ unsigned int Pw[4][16 * 20];              // 5 KB, pad 20 words
    __shared__ float Mx[4][2][16], Tx[4][2][16];         // 1 KB

    const int p  = blockIdx.x;
    const int b  = (p & 7) + 8 * ((p >> 3) >> 4);        // 2 batches per XCD
    const int qt = (p >> 3) & 15;

    const int t = threadIdx.x;
    const int lane = t & 63;
    const int w = t >> 6;
    const int wq = w & 3;          // q-chunk (16 rows)
    const int wd = w >> 2;         // kv-half (QK) / d-half (PV)
    const int lr = lane & 15;
    const int g  = lane >> 4;

    const bf16* Qg = Q  + ((size_t)b * NPOS + qt * QT) * CDIM;
    const bf16* Kg = K  + (size_t)b * NPOS * CDIM;
    const bf16* Vg = Vt + (size_t)b * CDIM * NPOS + (size_t)(wd * 256) * NPOS;

    // Q fragments: B-operand, row q = lr (wave's 16 rows), full d=512
    bf16x8 qf[16];
    {
        const bf16* qrow = Qg + (size_t)(wq * 16 + lr) * CDIM + g * 8;
        #pragma unroll
        for (int ds = 0; ds < 16; ds++) qf[ds] = *(const bf16x8*)(qrow + ds * 32);
    }

    f32x4 acc[16] = {};            // O^T[d-half][q]
    float m_run = -1e30f, l_run = 0.f;

    // prologue: stage K tile 0 into buf 0 (source col-chunk swizzled by row&7)
    #pragma unroll
    for (int i = 0; i < 4; i++) {
        int ci = t + i * 512;
        int r = ci >> 6, c = ci & 63;
        gload16(Kg + (size_t)r * CDIM + ((c ^ (r & 7)) * 8), &Klds[0][ci * 8]);
    }
    __syncthreads();

    for (int kt = 0; kt < 32; kt++) {
        const int cur = kt & 1;
        const int kv0 = kt * KVB;

        // V prefetch to regs (drained at barrier #1, consumed after #2)
        bf16x8 vf[16];
        #pragma unroll
        for (int d16 = 0; d16 < 16; d16++)
            vf[d16] = *(const bf16x8*)&Vg[(size_t)(d16 * 16 + lr) * NPOS + kv0 + g * 8];

        // stage K(kt+1) into the other buffer
        if (kt < 31) {
            const bf16* Kn = Kg + (size_t)(kv0 + KVB) * CDIM;
            #pragma unroll
            for (int i = 0; i < 4; i++) {
                int ci = t + i * 512;
                int r = ci >> 6, c = ci & 63;
                gload16(Kn + (size_t)r * CDIM + ((c ^ (r & 7)) * 8), &Klds[cur ^ 1][ci * 8]);
            }
        }

        // QK^T (swapped): S^T[kv-half wd][q], 16 MFMA in 4 independent chains
        const int krow = wd * 16 + lr;
        const bf16* kb = &Klds[cur][krow * CDIM];
        f32x4 sa = {}, sb = {}, sc = {}, sd = {};
        #pragma unroll
        for (int ds = 0; ds < 4; ds++) {
            const bf16x8 k0 = *(const bf16x8*)&kb[(((ds +  0) * 4 + g) ^ (lr & 7)) * 8];
            const bf16x8 k1 = *(const bf16x8*)&kb[(((ds +  4) * 4 + g) ^ (lr & 7)) * 8];
            const bf16x8 k2 = *(const bf16x8*)&kb[(((ds +  8) * 4 + g) ^ (lr & 7)) * 8];
            const bf16x8 k3 = *(const bf16x8*)&kb[(((ds + 12) * 4 + g) ^ (lr & 7)) * 8];
            sa = __builtin_amdgcn_mfma_f32_16x16x32_bf16(k0, qf[ds +  0], sa, 0, 0, 0);
            sb = __builtin_amdgcn_mfma_f32_16x16x32_bf16(k1, qf[ds +  4], sb, 0, 0, 0);
            sc = __builtin_amdgcn_mfma_f32_16x16x32_bf16(k2, qf[ds +  8], sc, 0, 0, 0);
            sd = __builtin_amdgcn_mfma_f32_16x16x32_bf16(k3, qf[ds + 12], sd, 0, 0, 0);
        }
        f32x4 s;
        #pragma unroll
        for (int i = 0; i < 4; i++) s[i] = (sa[i] + sb[i]) + (sc[i] + sd[i]);

        // half-tile row max, exchange across wd pair
        float mt = fmaxf(fmaxf(s[0], s[1]), fmaxf(s[2], s[3]));
        mt = fmaxf(mt, __shfl_xor(mt, 16));
        mt = fmaxf(mt, __shfl_xor(mt, 32));
        if (lane < 16) Mx[wq][wd][lane] = mt;
        __syncthreads();                       // #1: Mx ready; V/K loads drained

        const float mfull = fmaxf(mt, Mx[wq][wd ^ 1][lr]);
        const float m_new = (mfull > m_run + 8.f) ? mfull : m_run;  // defer-max
        const float p0 = __expf(s[0] - m_new), p1 = __expf(s[1] - m_new);
        const float p2 = __expf(s[2] - m_new), p3 = __expf(s[3] - m_new);
        float ts = p0 + p1 + p2 + p3;
        ts += __shfl_xor(ts, 16);
        ts += __shfl_xor(ts, 32);
        if (lane < 16) Tx[wq][wd][lane] = ts;
        Pw[wq][lr * 20 + wd * 8 + g * 2 + 0] = pk2(p0, p1);
        Pw[wq][lr * 20 + wd * 8 + g * 2 + 1] = pk2(p2, p3);
        __syncthreads();                       // #2: Tx + P ready

        const float tsf = ts + Tx[wq][wd ^ 1][lr];
        if (__any(m_new != m_run)) {
            const float alpha = __expf(m_run - m_new);
            #pragma unroll
            for (int i = 0; i < 16; i++) {
                acc[i][0] *= alpha; acc[i][1] *= alpha;
                acc[i][2] *= alpha; acc[i][3] *= alpha;
            }
            l_run *= alpha;
        }
        l_run += tsf;
        m_run = m_new;

        // PV: full-P B-operand, V-register A-operand, d-half output
        bf16x8 pf;
        {
            union { unsigned int u[4]; bf16x8 v; } cv;
            #pragma unroll
            for (int j = 0; j < 4; j++) cv.u[j] = Pw[wq][lr * 20 + g * 4 + j];
            pf = cv.v;
        }
        #pragma unroll
        for (int d16 = 0; d16 < 16; d16++)
            acc[d16] = __builtin_amdgcn_mfma_f32_16x16x32_bf16(vf[d16], pf, acc[d16], 0, 0, 0);
    }

    // epilogue
    const float inv = 1.f / l_run;
    bf16* Og = O + ((size_t)b * NPOS + qt * QT + wq * 16 + lr) * CDIM + wd * 256;
    #pragma unroll
    for (int d16 = 0; d16 < 16; d16++) {
        bf16x4 o;
        o[0] = (bf16)(acc[d16][0] * inv); o[1] = (bf16)(acc[d16][1] * inv);
        o[2] = (bf16)(acc[d16][2] * inv); o[3] = (bf16)(acc[d16][3] * inv);
        *(bf16x4*)(Og + d16 * 16 + g * 4) = o;
    }
}

// ---------------- proj GEMM + bias + residual (f32 out) ----------------
__global__ __launch_bounds__(256) void gemm_proj(
    const bf16* __restrict__ A, const bf16* __restrict__ Bw,
    const float* __restrict__ bias, float* __restrict__ Cp,
    const float* __restrict__ resid)
{
    __shared__ __align__(16) bf16 lsa[BM * BK];
    __shared__ __align__(16) bf16 lsb[BN * BK];
    const int bid = blockIdx.x;
    const int xcd = bid & 7;
    const int local = bid >> 3;               // 0..63
    const int colT = local & 3;
    const int rowT = (xcd << 4) + (local >> 2);
    const int bm = rowT * BM;
    const int bn = colT * BN;
    const int t = threadIdx.x;
    const int lane = t & 63;
    const int wid = t >> 6;
    const int wr = (wid >> 1) * 64;
    const int wc = (wid & 1) * 64;
    const int lr = lane & 15;
    const int ks = lane >> 4;
    const int r0 = t >> 2, c0 = (t & 3) * 8;
    const int r1 = (t + 256) >> 2, c1 = ((t + 256) & 3) * 8;

    f32x4 acc[4][4] = {};
    for (int k0 = 0; k0 < CDIM; k0 += BK) {
        gload16(&A[(size_t)(bm + r0) * CDIM + k0 + c0], &lsa[t * 8]);
        gload16(&A[(size_t)(bm + r1) * CDIM + k0 + c1], &lsa[(t + 256) * 8]);
        gload16(&Bw[(size_t)(bn + r0) * CDIM + k0 + c0], &lsb[t * 8]);
        gload16(&Bw[(size_t)(bn + r1) * CDIM + k0 + c1], &lsb[(t + 256) * 8]);
        __syncthreads();
        bf16x8 af[4], bfr[4];
        #pragma unroll
        for (int m = 0; m < 4; m++)
            af[m] = *(const bf16x8*)&lsa[(wr + m * 16 + lr) * BK + ks * 8];
        #pragma unroll
        for (int n = 0; n < 4; n++)
            bfr[n] = *(const bf16x8*)&lsb[(wc + n * 16 + lr) * BK + ks * 8];
        #pragma unroll
        for (int m = 0; m < 4; m++)
            #pragma unroll
            for (int n = 0; n < 4; n++)
                acc[m][n] = __builtin_amdgcn_mfma_f32_16x16x32_bf16(af[m], bfr[n], acc[m][n], 0, 0, 0);
        __syncthreads();
    }
    #pragma unroll
    for (int m = 0; m < 4; m++) {
        #pragma unroll
        for (int n = 0; n < 4; n++) {
            const int row0 = bm + wr + m * 16 + ks * 4;
            const int col  = bn + wc + n * 16 + lr;
            const float bvl = bias[col];
            #pragma unroll
            for (int r = 0; r < 4; r++) {
                const size_t idx = (size_t)(row0 + r) * CDIM + col;
                Cp[idx] = acc[m][n][r] + bvl + resid[idx];
            }
        }
    }
}

// ---------------- launch ----------------
extern "C" void kernel_launch(void* const* d_in, const int* in_sizes, int n_in,
                              void* d_out, int out_size, void* d_ws, size_t ws_size,
                              hipStream_t stream) {
    const float* x     = (const float*)d_in[0];
    const float* gamma = (const float*)d_in[1];
    const float* beta  = (const float*)d_in[2];
    const float* wq    = (const float*)d_in[3];
    const float* bq    = (const float*)d_in[4];
    const float* wk    = (const float*)d_in[5];
    const float* bk    = (const float*)d_in[6];
    const float* wv    = (const float*)d_in[7];
    const float* bv    = (const float*)d_in[8];
    const float* wp    = (const float*)d_in[9];
    const float* bp    = (const float*)d_in[10];

    char* ws = (char*)d_ws;
    bf16* wt = (bf16*)(ws + OFF_WT);
    bf16* xn = (bf16*)(ws + OFF_XN);
    bf16* Q  = (bf16*)(ws + OFF_Q);
    bf16* Km = (bf16*)(ws + OFF_K);
    bf16* Vt = (bf16*)(ws + OFF_VT);
    bf16* O  = (bf16*)(ws + OFF_O);

    transpose_cast<<<dim3(16, 16, 4), 256, 0, stream>>>(wq, wk, wv, wp, wt);
    groupnorm_kernel<<<dim3(512), 256, 0, stream>>>(x, gamma, beta, xn);

    const float qscale = 0.04419417382415922f;  // 512^-0.5 folded into Q
    gemm_qkv<<<dim3(1536), 256, 0, stream>>>(
        xn, wt, bq, bk, bv, qscale, Q, Km, Vt);

    flash_attn<<<dim3(256), 512, 0, stream>>>(Q, Km, Vt, O);

    gemm_proj<<<dim3(512), 256, 0, stream>>>(
        O, wt + (size_t)3 * WELEMS, bp, (float*)d_out, x);
}

// Round 7
// 340.949 us; speedup vs baseline: 1.0817x; 1.0817x over previous
//
#include <hip/hip_runtime.h>

typedef __bf16 bf16;
typedef __bf16 bf16x8 __attribute__((ext_vector_type(8)));
typedef __bf16 bf16x4 __attribute__((ext_vector_type(4)));
typedef float  f32x4  __attribute__((ext_vector_type(4)));

#define CDIM   512
#define NPOS   1024
#define NBATCH 16
#define MTOT   (NBATCH * NPOS)
#define WELEMS (CDIM * CDIM)

// ---------------- workspace layout (bytes) ----------------
#define OFF_WT  ((size_t)0)
#define OFF_XN  ((size_t)(2 * 1024 * 1024))
#define OFF_Q   (OFF_XN + (size_t)MTOT * CDIM * 2)
#define OFF_K   (OFF_Q  + (size_t)MTOT * CDIM * 2)
#define OFF_VT  (OFF_K  + (size_t)MTOT * CDIM * 2)
#define OFF_O   OFF_XN   // xn dead after QKV GEMM; reuse for O

// async global->LDS, 16B per lane. LDS dest must be wave-uniform base + lane*16.
__device__ __forceinline__ void gload16(const bf16* g, bf16* l) {
    __builtin_amdgcn_global_load_lds(
        (const __attribute__((address_space(1))) void*)g,
        (__attribute__((address_space(3))) void*)l, 16, 0, 0);
}

__device__ __forceinline__ unsigned int pk2(float lo, float hi) {
    union { bf16 h; unsigned short s; } a, c;
    a.h = (bf16)lo; c.h = (bf16)hi;
    return (unsigned int)a.s | ((unsigned int)c.s << 16);
}

// ---------------- weight transpose + cast ----------------
__global__ __launch_bounds__(256) void transpose_cast(
    const float* __restrict__ w0, const float* __restrict__ w1,
    const float* __restrict__ w2, const float* __restrict__ w3,
    bf16* __restrict__ wt)
{
    __shared__ bf16 tile[32][33];
    int z = blockIdx.z;
    const float* W = (z == 0) ? w0 : (z == 1) ? w1 : (z == 2) ? w2 : w3;
    bf16* out = wt + (size_t)z * WELEMS;
    int bx = blockIdx.x * 32;
    int by = blockIdx.y * 32;
    int tx = threadIdx.x & 31, ty = threadIdx.x >> 5;
    #pragma unroll
    for (int i = ty; i < 32; i += 8)
        tile[i][tx] = (bf16)W[(size_t)(by + i) * CDIM + bx + tx];
    __syncthreads();
    #pragma unroll
    for (int i = ty; i < 32; i += 8)
        out[(size_t)(bx + i) * CDIM + by + tx] = tile[tx][i];
}

// ---------------- GroupNorm -> bf16 ----------------
__global__ __launch_bounds__(256) void groupnorm_kernel(
    const float* __restrict__ x, const float* __restrict__ gamma,
    const float* __restrict__ beta, bf16* __restrict__ xn)
{
    int b = blockIdx.x >> 5;
    int g = blockIdx.x & 31;
    const float* xb = x + (size_t)b * NPOS * CDIM;
    int t = threadIdx.x, lane = t & 63, wid = t >> 6;

    float s = 0.f, s2 = 0.f;
    for (int i = t; i < 4096; i += 256) {
        int n = i >> 2, c4 = i & 3;
        const float4 v = *(const float4*)&xb[n * CDIM + g * 16 + c4 * 4];
        s  += v.x + v.y + v.z + v.w;
        s2 += v.x * v.x + v.y * v.y + v.z * v.z + v.w * v.w;
    }
    #pragma unroll
    for (int o = 32; o; o >>= 1) { s += __shfl_xor(s, o); s2 += __shfl_xor(s2, o); }
    __shared__ float rs[4], rs2[4];
    if (lane == 0) { rs[wid] = s; rs2[wid] = s2; }
    __syncthreads();
    float S  = rs[0] + rs[1] + rs[2] + rs[3];
    float S2 = rs2[0] + rs2[1] + rs2[2] + rs2[3];
    const float inv_n = 1.f / 16384.f;
    float mean = S * inv_n;
    float var  = S2 * inv_n - mean * mean;
    float rstd = rsqrtf(var + 1e-3f);

    bf16* xnb = xn + (size_t)b * NPOS * CDIM;
    for (int i = t; i < 4096; i += 256) {
        int n = i >> 2, c4 = i & 3;
        int c = g * 16 + c4 * 4;
        const float4 v = *(const float4*)&xb[n * CDIM + c];
        bf16x4 o;
        o[0] = (bf16)(((v.x - mean) * rstd) * gamma[c + 0] + beta[c + 0]);
        o[1] = (bf16)(((v.y - mean) * rstd) * gamma[c + 1] + beta[c + 1]);
        o[2] = (bf16)(((v.z - mean) * rstd) * gamma[c + 2] + beta[c + 2]);
        o[3] = (bf16)(((v.w - mean) * rstd) * gamma[c + 3] + beta[c + 3]);
        *(bf16x4*)&xnb[n * CDIM + c] = o;
    }
}

// ---------------- fused QKV GEMM: [16384,512] x [512,1536] ----------------
#define BM 128
#define BN 128
#define BK 32

__global__ __launch_bounds__(256) void gemm_qkv(
    const bf16* __restrict__ A, const bf16* __restrict__ Bw,
    const float* __restrict__ bq, const float* __restrict__ bk,
    const float* __restrict__ bv, float qscale,
    bf16* __restrict__ Qo, bf16* __restrict__ Ko, bf16* __restrict__ Vto)
{
    __shared__ __align__(16) bf16 lsa[BM * BK];
    __shared__ __align__(16) bf16 lsb[BN * BK];
    const int bid = blockIdx.x;
    const int xcd = bid & 7;
    const int local = bid >> 3;               // 0..191
    const int colT = local % 12;
    const int rowT = (xcd << 4) + local / 12; // 0..127
    const int bm = rowT * BM;
    const int bnG = colT * BN;
    const int region = colT >> 2;             // 0=Q 1=K 2=V
    const int t = threadIdx.x;
    const int lane = t & 63;
    const int wid = t >> 6;
    const int wr = (wid >> 1) * 64;
    const int wc = (wid & 1) * 64;
    const int lr = lane & 15;
    const int ks = lane >> 4;

    const int r0 = t >> 2, c0 = (t & 3) * 8;
    const int r1 = (t + 256) >> 2, c1 = ((t + 256) & 3) * 8;

    f32x4 acc[4][4] = {};

    for (int k0 = 0; k0 < CDIM; k0 += BK) {
        gload16(&A[(size_t)(bm + r0) * CDIM + k0 + c0], &lsa[t * 8]);
        gload16(&A[(size_t)(bm + r1) * CDIM + k0 + c1], &lsa[(t + 256) * 8]);
        gload16(&Bw[(size_t)(bnG + r0) * CDIM + k0 + c0], &lsb[t * 8]);
        gload16(&Bw[(size_t)(bnG + r1) * CDIM + k0 + c1], &lsb[(t + 256) * 8]);
        __syncthreads();
        bf16x8 af[4], bfr[4];
        #pragma unroll
        for (int m = 0; m < 4; m++)
            af[m] = *(const bf16x8*)&lsa[(wr + m * 16 + lr) * BK + ks * 8];
        #pragma unroll
        for (int n = 0; n < 4; n++)
            bfr[n] = *(const bf16x8*)&lsb[(wc + n * 16 + lr) * BK + ks * 8];
        #pragma unroll
        for (int m = 0; m < 4; m++)
            #pragma unroll
            for (int n = 0; n < 4; n++)
                acc[m][n] = __builtin_amdgcn_mfma_f32_16x16x32_bf16(af[m], bfr[n], acc[m][n], 0, 0, 0);
        __syncthreads();
    }

    const float* bias = (region == 0) ? bq : (region == 1) ? bk : bv;
    const float scale = (region == 0) ? qscale : 1.f;
    #pragma unroll
    for (int m = 0; m < 4; m++) {
        #pragma unroll
        for (int n = 0; n < 4; n++) {
            const int row0 = bm + wr + m * 16 + ks * 4;
            const int colG = bnG + wc + n * 16 + lr;
            const int cl = colG - region * CDIM;
            const float bvl = bias[cl];
            #pragma unroll
            for (int r = 0; r < 4; r++) {
                const int rr = row0 + r;
                const float v = (acc[m][n][r] + bvl) * scale;
                if (region == 0) {
                    Qo[(size_t)rr * CDIM + cl] = (bf16)v;
                } else if (region == 1) {
                    Ko[(size_t)rr * CDIM + cl] = (bf16)v;
                } else {
                    const int bb = rr >> 10, nn = rr & 1023;
                    Vto[(size_t)bb * CDIM * NPOS + (size_t)cl * NPOS + nn] = (bf16)v;
                }
            }
        }
    }
}

// ---------------- flash attention (8 waves, 2/SIMD, 1 block/CU) ----------------
// LDS deliberately > 80KB: forces the backend's occupancy target to 1 block/CU
// (8 waves = 2/SIMD) so the VGPR cap is 256, not 128 (which spilled: r5/r6).
// K swizzle uses r&15 (4-way max conflict); old r&7 gave 8-way.
#define QT 64
#define KVB 32
#define KPAD 2880   // pad each K buffer: total LDS 83.2KB > 80KB

__global__ __launch_bounds__(512, 1) void flash_attn(
    const bf16* __restrict__ Q, const bf16* __restrict__ K,
    const bf16* __restrict__ Vt, bf16* __restrict__ O)
{
    __shared__ __align__(16) bf16 Klds[2][KVB * CDIM + KPAD];  // 78.3 KB
    __shared__ unsigned int Pw[4][16 * 20];                    // 5 KB
    __shared__ float Mx[4][2][16], Tx[4][2][16];               // 1 KB

    const int p  = blockIdx.x;
    const int b  = (p & 7) + 8 * ((p >> 3) >> 4);        // 2 batches per XCD
    const int qt = (p >> 3) & 15;

    const int t = threadIdx.x;
    const int lane = t & 63;
    const int w = t >> 6;
    const int wq = w & 3;          // q-chunk (16 rows)
    const int wd = w >> 2;         // kv-half (QK) / d-half (PV)
    const int lr = lane & 15;
    const int g  = lane >> 4;

    const bf16* Qg = Q  + ((size_t)b * NPOS + qt * QT) * CDIM;
    const bf16* Kg = K  + (size_t)b * NPOS * CDIM;
    const bf16* Vg = Vt + (size_t)b * CDIM * NPOS + (size_t)(wd * 256) * NPOS;

    // Q fragments: B-operand, row q = lr (wave's 16 rows), full d=512
    bf16x8 qf[16];
    {
        const bf16* qrow = Qg + (size_t)(wq * 16 + lr) * CDIM + g * 8;
        #pragma unroll
        for (int ds = 0; ds < 16; ds++) qf[ds] = *(const bf16x8*)(qrow + ds * 32);
    }

    f32x4 acc[16] = {};            // O^T[d-half][q]
    float m_run = -1e30f, l_run = 0.f;

    // prologue: stage K tile 0 (source chunk swizzled: c ^ (r&15))
    #pragma unroll
    for (int i = 0; i < 4; i++) {
        int ci = t + i * 512;
        int r = ci >> 6, c = ci & 63;
        gload16(Kg + (size_t)r * CDIM + ((c ^ (r & 15)) * 8), &Klds[0][ci * 8]);
    }
    __syncthreads();

    for (int kt = 0; kt < 32; kt++) {
        const int cur = kt & 1;
        const int kv0 = kt * KVB;

        // V first-half prefetch to regs (rides across barrier #1, used after #2)
        bf16x8 vf[8];
        #pragma unroll
        for (int d16 = 0; d16 < 8; d16++)
            vf[d16] = *(const bf16x8*)&Vg[(size_t)(d16 * 16 + lr) * NPOS + kv0 + g * 8];

        // stage K(kt+1) into the other buffer
        if (kt < 31) {
            const bf16* Kn = Kg + (size_t)(kv0 + KVB) * CDIM;
            #pragma unroll
            for (int i = 0; i < 4; i++) {
                int ci = t + i * 512;
                int r = ci >> 6, c = ci & 63;
                gload16(Kn + (size_t)r * CDIM + ((c ^ (r & 15)) * 8), &Klds[cur ^ 1][ci * 8]);
            }
        }

        // QK^T (swapped): S^T[kv-half wd][q], 16 MFMA in 4 independent chains
        const int krow = wd * 16 + lr;
        const bf16* kb = &Klds[cur][krow * CDIM];
        f32x4 sa = {}, sb = {}, sc = {}, sd = {};
        #pragma unroll
        for (int ds = 0; ds < 4; ds++) {
            const bf16x8 k0 = *(const bf16x8*)&kb[(((ds +  0) * 4 + g) ^ lr) * 8];
            const bf16x8 k1 = *(const bf16x8*)&kb[(((ds +  4) * 4 + g) ^ lr) * 8];
            const bf16x8 k2 = *(const bf16x8*)&kb[(((ds +  8) * 4 + g) ^ lr) * 8];
            const bf16x8 k3 = *(const bf16x8*)&kb[(((ds + 12) * 4 + g) ^ lr) * 8];
            sa = __builtin_amdgcn_mfma_f32_16x16x32_bf16(k0, qf[ds +  0], sa, 0, 0, 0);
            sb = __builtin_amdgcn_mfma_f32_16x16x32_bf16(k1, qf[ds +  4], sb, 0, 0, 0);
            sc = __builtin_amdgcn_mfma_f32_16x16x32_bf16(k2, qf[ds +  8], sc, 0, 0, 0);
            sd = __builtin_amdgcn_mfma_f32_16x16x32_bf16(k3, qf[ds + 12], sd, 0, 0, 0);
        }
        f32x4 s;
        #pragma unroll
        for (int i = 0; i < 4; i++) s[i] = (sa[i] + sb[i]) + (sc[i] + sd[i]);

        // half-tile row max, exchange across wd pair
        float mt = fmaxf(fmaxf(s[0], s[1]), fmaxf(s[2], s[3]));
        mt = fmaxf(mt, __shfl_xor(mt, 16));
        mt = fmaxf(mt, __shfl_xor(mt, 32));
        if (lane < 16) Mx[wq][wd][lane] = mt;
        __syncthreads();                       // #1: Mx ready; V/K loads drained

        const float mfull = fmaxf(mt, Mx[wq][wd ^ 1][lr]);
        const float m_new = (mfull > m_run + 8.f) ? mfull : m_run;  // defer-max
        const float p0 = __expf(s[0] - m_new), p1 = __expf(s[1] - m_new);
        const float p2 = __expf(s[2] - m_new), p3 = __expf(s[3] - m_new);
        float ts = p0 + p1 + p2 + p3;
        ts += __shfl_xor(ts, 16);
        ts += __shfl_xor(ts, 32);
        if (lane < 16) Tx[wq][wd][lane] = ts;
        Pw[wq][lr * 20 + wd * 8 + g * 2 + 0] = pk2(p0, p1);
        Pw[wq][lr * 20 + wd * 8 + g * 2 + 1] = pk2(p2, p3);
        __syncthreads();                       // #2: Tx + P ready

        const float tsf = ts + Tx[wq][wd ^ 1][lr];
        if (__any(m_new != m_run)) {
            const float alpha = __expf(m_run - m_new);
            #pragma unroll
            for (int i = 0; i < 16; i++) {
                acc[i][0] *= alpha; acc[i][1] *= alpha;
                acc[i][2] *= alpha; acc[i][3] *= alpha;
            }
            l_run *= alpha;
        }
        l_run += tsf;
        m_run = m_new;

        // PV: P B-operand; V A-operand (half prefetched, half loaded here)
        bf16x8 pf;
        {
            union { unsigned int u[4]; bf16x8 v; } cv;
            #pragma unroll
            for (int j = 0; j < 4; j++) cv.u[j] = Pw[wq][lr * 20 + g * 4 + j];
            pf = cv.v;
        }
        bf16x8 vf2[8];
        #pragma unroll
        for (int d16 = 0; d16 < 8; d16++)
            vf2[d16] = *(const bf16x8*)&Vg[(size_t)((d16 + 8) * 16 + lr) * NPOS + kv0 + g * 8];
        #pragma unroll
        for (int d16 = 0; d16 < 8; d16++)
            acc[d16] = __builtin_amdgcn_mfma_f32_16x16x32_bf16(vf[d16], pf, acc[d16], 0, 0, 0);
        #pragma unroll
        for (int d16 = 0; d16 < 8; d16++)
            acc[d16 + 8] = __builtin_amdgcn_mfma_f32_16x16x32_bf16(vf2[d16], pf, acc[d16 + 8], 0, 0, 0);
    }

    // epilogue
    const float inv = 1.f / l_run;
    bf16* Og = O + ((size_t)b * NPOS + qt * QT + wq * 16 + lr) * CDIM + wd * 256;
    #pragma unroll
    for (int d16 = 0; d16 < 16; d16++) {
        bf16x4 o;
        o[0] = (bf16)(acc[d16][0] * inv); o[1] = (bf16)(acc[d16][1] * inv);
        o[2] = (bf16)(acc[d16][2] * inv); o[3] = (bf16)(acc[d16][3] * inv);
        *(bf16x4*)(Og + d16 * 16 + g * 4) = o;
    }
}

// ---------------- proj GEMM + bias + residual (f32 out) ----------------
__global__ __launch_bounds__(256) void gemm_proj(
    const bf16* __restrict__ A, const bf16* __restrict__ Bw,
    const float* __restrict__ bias, float* __restrict__ Cp,
    const float* __restrict__ resid)
{
    __shared__ __align__(16) bf16 lsa[BM * BK];
    __shared__ __align__(16) bf16 lsb[BN * BK];
    const int bid = blockIdx.x;
    const int xcd = bid & 7;
    const int local = bid >> 3;               // 0..63
    const int colT = local & 3;
    const int rowT = (xcd << 4) + (local >> 2);
    const int bm = rowT * BM;
    const int bn = colT * BN;
    const int t = threadIdx.x;
    const int lane = t & 63;
    const int wid = t >> 6;
    const int wr = (wid >> 1) * 64;
    const int wc = (wid & 1) * 64;
    const int lr = lane & 15;
    const int ks = lane >> 4;
    const int r0 = t >> 2, c0 = (t & 3) * 8;
    const int r1 = (t + 256) >> 2, c1 = ((t + 256) & 3) * 8;

    f32x4 acc[4][4] = {};
    for (int k0 = 0; k0 < CDIM; k0 += BK) {
        gload16(&A[(size_t)(bm + r0) * CDIM + k0 + c0], &lsa[t * 8]);
        gload16(&A[(size_t)(bm + r1) * CDIM + k0 + c1], &lsa[(t + 256) * 8]);
        gload16(&Bw[(size_t)(bn + r0) * CDIM + k0 + c0], &lsb[t * 8]);
        gload16(&Bw[(size_t)(bn + r1) * CDIM + k0 + c1], &lsb[(t + 256) * 8]);
        __syncthreads();
        bf16x8 af[4], bfr[4];
        #pragma unroll
        for (int m = 0; m < 4; m++)
            af[m] = *(const bf16x8*)&lsa[(wr + m * 16 + lr) * BK + ks * 8];
        #pragma unroll
        for (int n = 0; n < 4; n++)
            bfr[n] = *(const bf16x8*)&lsb[(wc + n * 16 + lr) * BK + ks * 8];
        #pragma unroll
        for (int m = 0; m < 4; m++)
            #pragma unroll
            for (int n = 0; n < 4; n++)
                acc[m][n] = __builtin_amdgcn_mfma_f32_16x16x32_bf16(af[m], bfr[n], acc[m][n], 0, 0, 0);
        __syncthreads();
    }
    #pragma unroll
    for (int m = 0; m < 4; m++) {
        #pragma unroll
        for (int n = 0; n < 4; n++) {
            const int row0 = bm + wr + m * 16 + ks * 4;
            const int col  = bn + wc + n * 16 + lr;
            const float bvl = bias[col];
            #pragma unroll
            for (int r = 0; r < 4; r++) {
                const size_t idx = (size_t)(row0 + r) * CDIM + col;
                Cp[idx] = acc[m][n][r] + bvl + resid[idx];
            }
        }
    }
}

// ---------------- launch ----------------
extern "C" void kernel_launch(void* const* d_in, const int* in_sizes, int n_in,
                              void* d_out, int out_size, void* d_ws, size_t ws_size,
                              hipStream_t stream) {
    const float* x     = (const float*)d_in[0];
    const float* gamma = (const float*)d_in[1];
    const float* beta  = (const float*)d_in[2];
    const float* wq    = (const float*)d_in[3];
    const float* bq    = (const float*)d_in[4];
    const float* wk    = (const float*)d_in[5];
    const float* bk    = (const float*)d_in[6];
    const float* wv    = (const float*)d_in[7];
    const float* bv    = (const float*)d_in[8];
    const float* wp    = (const float*)d_in[9];
    const float* bp    = (const float*)d_in[10];

    char* ws = (char*)d_ws;
    bf16* wt = (bf16*)(ws + OFF_WT);
    bf16* xn = (bf16*)(ws + OFF_XN);
    bf16* Q  = (bf16*)(ws + OFF_Q);
    bf16* Km = (bf16*)(ws + OFF_K);
    bf16* Vt = (bf16*)(ws + OFF_VT);
    bf16* O  = (bf16*)(ws + OFF_O);

    transpose_cast<<<dim3(16, 16, 4), 256, 0, stream>>>(wq, wk, wv, wp, wt);
    groupnorm_kernel<<<dim3(512), 256, 0, stream>>>(x, gamma, beta, xn);

    const float qscale = 0.04419417382415922f;  // 512^-0.5 folded into Q
    gemm_qkv<<<dim3(1536), 256, 0, stream>>>(
        xn, wt, bq, bk, bv, qscale, Q, Km, Vt);

    flash_attn<<<dim3(256), 512, 0, stream>>>(Q, Km, Vt, O);

    gemm_proj<<<dim3(512), 256, 0, stream>>>(
        O, wt + (size_t)3 * WELEMS, bp, (float*)d_out, x);
}

// Round 8
// 338.923 us; speedup vs baseline: 1.0881x; 1.0060x over previous
//
#include <hip/hip_runtime.h>

typedef __bf16 bf16;
typedef __bf16 bf16x8 __attribute__((ext_vector_type(8)));
typedef __bf16 bf16x4 __attribute__((ext_vector_type(4)));
typedef float  f32x4  __attribute__((ext_vector_type(4)));

#define CDIM   512
#define NPOS   1024
#define NBATCH 16
#define MTOT   (NBATCH * NPOS)
#define WELEMS (CDIM * CDIM)

// ---------------- workspace layout (bytes) ----------------
#define OFF_WT  ((size_t)0)
#define OFF_XN  ((size_t)(2 * 1024 * 1024))
#define OFF_Q   (OFF_XN + (size_t)MTOT * CDIM * 2)
#define OFF_K   (OFF_Q  + (size_t)MTOT * CDIM * 2)
#define OFF_VT  (OFF_K  + (size_t)MTOT * CDIM * 2)
#define OFF_O   OFF_XN   // xn dead after QKV GEMM; reuse for O

// async global->LDS, 16B per lane. LDS dest must be wave-uniform base + lane*16.
__device__ __forceinline__ void gload16(const bf16* g, bf16* l) {
    __builtin_amdgcn_global_load_lds(
        (const __attribute__((address_space(1))) void*)g,
        (__attribute__((address_space(3))) void*)l, 16, 0, 0);
}

__device__ __forceinline__ unsigned int pk2(float lo, float hi) {
    union { bf16 h; unsigned short s; } a, c;
    a.h = (bf16)lo; c.h = (bf16)hi;
    return (unsigned int)a.s | ((unsigned int)c.s << 16);
}

// ---------------- weight transpose + cast ----------------
__global__ __launch_bounds__(256) void transpose_cast(
    const float* __restrict__ w0, const float* __restrict__ w1,
    const float* __restrict__ w2, const float* __restrict__ w3,
    bf16* __restrict__ wt)
{
    __shared__ bf16 tile[32][33];
    int z = blockIdx.z;
    const float* W = (z == 0) ? w0 : (z == 1) ? w1 : (z == 2) ? w2 : w3;
    bf16* out = wt + (size_t)z * WELEMS;
    int bx = blockIdx.x * 32;
    int by = blockIdx.y * 32;
    int tx = threadIdx.x & 31, ty = threadIdx.x >> 5;
    #pragma unroll
    for (int i = ty; i < 32; i += 8)
        tile[i][tx] = (bf16)W[(size_t)(by + i) * CDIM + bx + tx];
    __syncthreads();
    #pragma unroll
    for (int i = ty; i < 32; i += 8)
        out[(size_t)(bx + i) * CDIM + by + tx] = tile[tx][i];
}

// ---------------- GroupNorm -> bf16 ----------------
__global__ __launch_bounds__(256) void groupnorm_kernel(
    const float* __restrict__ x, const float* __restrict__ gamma,
    const float* __restrict__ beta, bf16* __restrict__ xn)
{
    int b = blockIdx.x >> 5;
    int g = blockIdx.x & 31;
    const float* xb = x + (size_t)b * NPOS * CDIM;
    int t = threadIdx.x, lane = t & 63, wid = t >> 6;

    float s = 0.f, s2 = 0.f;
    for (int i = t; i < 4096; i += 256) {
        int n = i >> 2, c4 = i & 3;
        const float4 v = *(const float4*)&xb[n * CDIM + g * 16 + c4 * 4];
        s  += v.x + v.y + v.z + v.w;
        s2 += v.x * v.x + v.y * v.y + v.z * v.z + v.w * v.w;
    }
    #pragma unroll
    for (int o = 32; o; o >>= 1) { s += __shfl_xor(s, o); s2 += __shfl_xor(s2, o); }
    __shared__ float rs[4], rs2[4];
    if (lane == 0) { rs[wid] = s; rs2[wid] = s2; }
    __syncthreads();
    float S  = rs[0] + rs[1] + rs[2] + rs[3];
    float S2 = rs2[0] + rs2[1] + rs2[2] + rs2[3];
    const float inv_n = 1.f / 16384.f;
    float mean = S * inv_n;
    float var  = S2 * inv_n - mean * mean;
    float rstd = rsqrtf(var + 1e-3f);

    bf16* xnb = xn + (size_t)b * NPOS * CDIM;
    for (int i = t; i < 4096; i += 256) {
        int n = i >> 2, c4 = i & 3;
        int c = g * 16 + c4 * 4;
        const float4 v = *(const float4*)&xb[n * CDIM + c];
        bf16x4 o;
        o[0] = (bf16)(((v.x - mean) * rstd) * gamma[c + 0] + beta[c + 0]);
        o[1] = (bf16)(((v.y - mean) * rstd) * gamma[c + 1] + beta[c + 1]);
        o[2] = (bf16)(((v.z - mean) * rstd) * gamma[c + 2] + beta[c + 2]);
        o[3] = (bf16)(((v.w - mean) * rstd) * gamma[c + 3] + beta[c + 3]);
        *(bf16x4*)&xnb[n * CDIM + c] = o;
    }
}

// ---------------- fused QKV GEMM: [16384,512] x [512,1536] ----------------
#define BM 128
#define BN 128
#define BK 32

__global__ __launch_bounds__(256) void gemm_qkv(
    const bf16* __restrict__ A, const bf16* __restrict__ Bw,
    const float* __restrict__ bq, const float* __restrict__ bk,
    const float* __restrict__ bv, float qscale,
    bf16* __restrict__ Qo, bf16* __restrict__ Ko, bf16* __restrict__ Vto)
{
    __shared__ __align__(16) bf16 lsa[BM * BK];
    __shared__ __align__(16) bf16 lsb[BN * BK];
    const int bid = blockIdx.x;
    const int xcd = bid & 7;
    const int local = bid >> 3;               // 0..191
    const int colT = local % 12;
    const int rowT = (xcd << 4) + local / 12; // 0..127
    const int bm = rowT * BM;
    const int bnG = colT * BN;
    const int region = colT >> 2;             // 0=Q 1=K 2=V
    const int t = threadIdx.x;
    const int lane = t & 63;
    const int wid = t >> 6;
    const int wr = (wid >> 1) * 64;
    const int wc = (wid & 1) * 64;
    const int lr = lane & 15;
    const int ks = lane >> 4;

    const int r0 = t >> 2, c0 = (t & 3) * 8;
    const int r1 = (t + 256) >> 2, c1 = ((t + 256) & 3) * 8;

    f32x4 acc[4][4] = {};

    for (int k0 = 0; k0 < CDIM; k0 += BK) {
        gload16(&A[(size_t)(bm + r0) * CDIM + k0 + c0], &lsa[t * 8]);
        gload16(&A[(size_t)(bm + r1) * CDIM + k0 + c1], &lsa[(t + 256) * 8]);
        gload16(&Bw[(size_t)(bnG + r0) * CDIM + k0 + c0], &lsb[t * 8]);
        gload16(&Bw[(size_t)(bnG + r1) * CDIM + k0 + c1], &lsb[(t + 256) * 8]);
        __syncthreads();
        bf16x8 af[4], bfr[4];
        #pragma unroll
        for (int m = 0; m < 4; m++)
            af[m] = *(const bf16x8*)&lsa[(wr + m * 16 + lr) * BK + ks * 8];
        #pragma unroll
        for (int n = 0; n < 4; n++)
            bfr[n] = *(const bf16x8*)&lsb[(wc + n * 16 + lr) * BK + ks * 8];
        #pragma unroll
        for (int m = 0; m < 4; m++)
            #pragma unroll
            for (int n = 0; n < 4; n++)
                acc[m][n] = __builtin_amdgcn_mfma_f32_16x16x32_bf16(af[m], bfr[n], acc[m][n], 0, 0, 0);
        __syncthreads();
    }

    const float* bias = (region == 0) ? bq : (region == 1) ? bk : bv;
    const float scale = (region == 0) ? qscale : 1.f;
    #pragma unroll
    for (int m = 0; m < 4; m++) {
        #pragma unroll
        for (int n = 0; n < 4; n++) {
            const int row0 = bm + wr + m * 16 + ks * 4;
            const int colG = bnG + wc + n * 16 + lr;
            const int cl = colG - region * CDIM;
            const float bvl = bias[cl];
            #pragma unroll
            for (int r = 0; r < 4; r++) {
                const int rr = row0 + r;
                const float v = (acc[m][n][r] + bvl) * scale;
                if (region == 0) {
                    Qo[(size_t)rr * CDIM + cl] = (bf16)v;
                } else if (region == 1) {
                    Ko[(size_t)rr * CDIM + cl] = (bf16)v;
                } else {
                    const int bb = rr >> 10, nn = rr & 1023;
                    Vto[(size_t)bb * CDIM * NPOS + (size_t)cl * NPOS + nn] = (bf16)v;
                }
            }
        }
    }
}

// ---------------- flash attention (8 waves, 2/SIMD, 1 block/CU) ----------------
// amdgpu_waves_per_eu(2,2): pin the backend's occupancy target to exactly
// 2 waves/EU -> VGPR budget 256/wave. Without it the heuristic targeted ~4
// waves/EU and squeezed to 120-128 VGPR with spills (r5/r6/r7: 143-175us).
// LDS > 80KB keeps 1 block/CU. K source-swizzle c^(r&15): 4-way max conflict.
#define QT 64
#define KVB 32
#define KPAD 2880   // pad each K buffer: total LDS 83.2KB > 80KB

__global__ __launch_bounds__(512, 1) __attribute__((amdgpu_waves_per_eu(2, 2)))
void flash_attn(
    const bf16* __restrict__ Q, const bf16* __restrict__ K,
    const bf16* __restrict__ Vt, bf16* __restrict__ O)
{
    __shared__ __align__(16) bf16 Klds[2][KVB * CDIM + KPAD];  // 78.3 KB
    __shared__ unsigned int Pw[4][16 * 20];                    // 5 KB
    __shared__ float Mx[4][2][16], Tx[4][2][16];               // 1 KB

    const int p  = blockIdx.x;
    const int b  = (p & 7) + 8 * ((p >> 3) >> 4);        // 2 batches per XCD
    const int qt = (p >> 3) & 15;

    const int t = threadIdx.x;
    const int lane = t & 63;
    const int w = t >> 6;
    const int wq = w & 3;          // q-chunk (16 rows)
    const int wd = w >> 2;         // kv-half (QK) / d-half (PV)
    const int lr = lane & 15;
    const int g  = lane >> 4;

    const bf16* Qg = Q  + ((size_t)b * NPOS + qt * QT) * CDIM;
    const bf16* Kg = K  + (size_t)b * NPOS * CDIM;
    const bf16* Vg = Vt + (size_t)b * CDIM * NPOS + (size_t)(wd * 256) * NPOS;

    // Q fragments: B-operand, row q = lr (wave's 16 rows), full d=512
    bf16x8 qf[16];
    {
        const bf16* qrow = Qg + (size_t)(wq * 16 + lr) * CDIM + g * 8;
        #pragma unroll
        for (int ds = 0; ds < 16; ds++) qf[ds] = *(const bf16x8*)(qrow + ds * 32);
    }

    f32x4 acc[16] = {};            // O^T[d-half][q]
    float m_run = -1e30f, l_run = 0.f;

    // prologue: stage K tile 0 (source chunk swizzled: c ^ (r&15))
    #pragma unroll
    for (int i = 0; i < 4; i++) {
        int ci = t + i * 512;
        int r = ci >> 6, c = ci & 63;
        gload16(Kg + (size_t)r * CDIM + ((c ^ (r & 15)) * 8), &Klds[0][ci * 8]);
    }
    __syncthreads();

    for (int kt = 0; kt < 32; kt++) {
        const int cur = kt & 1;
        const int kv0 = kt * KVB;

        // V first-half prefetch to regs (rides across barrier #1, used after #2)
        bf16x8 vf[8];
        #pragma unroll
        for (int d16 = 0; d16 < 8; d16++)
            vf[d16] = *(const bf16x8*)&Vg[(size_t)(d16 * 16 + lr) * NPOS + kv0 + g * 8];

        // stage K(kt+1) into the other buffer
        if (kt < 31) {
            const bf16* Kn = Kg + (size_t)(kv0 + KVB) * CDIM;
            #pragma unroll
            for (int i = 0; i < 4; i++) {
                int ci = t + i * 512;
                int r = ci >> 6, c = ci & 63;
                gload16(Kn + (size_t)r * CDIM + ((c ^ (r & 15)) * 8), &Klds[cur ^ 1][ci * 8]);
            }
        }

        // QK^T (swapped): S^T[kv-half wd][q], 16 MFMA in 4 independent chains
        const int krow = wd * 16 + lr;
        const bf16* kb = &Klds[cur][krow * CDIM];
        f32x4 sa = {}, sb = {}, sc = {}, sd = {};
        #pragma unroll
        for (int ds = 0; ds < 4; ds++) {
            const bf16x8 k0 = *(const bf16x8*)&kb[(((ds +  0) * 4 + g) ^ lr) * 8];
            const bf16x8 k1 = *(const bf16x8*)&kb[(((ds +  4) * 4 + g) ^ lr) * 8];
            const bf16x8 k2 = *(const bf16x8*)&kb[(((ds +  8) * 4 + g) ^ lr) * 8];
            const bf16x8 k3 = *(const bf16x8*)&kb[(((ds + 12) * 4 + g) ^ lr) * 8];
            sa = __builtin_amdgcn_mfma_f32_16x16x32_bf16(k0, qf[ds +  0], sa, 0, 0, 0);
            sb = __builtin_amdgcn_mfma_f32_16x16x32_bf16(k1, qf[ds +  4], sb, 0, 0, 0);
            sc = __builtin_amdgcn_mfma_f32_16x16x32_bf16(k2, qf[ds +  8], sc, 0, 0, 0);
            sd = __builtin_amdgcn_mfma_f32_16x16x32_bf16(k3, qf[ds + 12], sd, 0, 0, 0);
        }
        f32x4 s;
        #pragma unroll
        for (int i = 0; i < 4; i++) s[i] = (sa[i] + sb[i]) + (sc[i] + sd[i]);

        // half-tile row max, exchange across wd pair
        float mt = fmaxf(fmaxf(s[0], s[1]), fmaxf(s[2], s[3]));
        mt = fmaxf(mt, __shfl_xor(mt, 16));
        mt = fmaxf(mt, __shfl_xor(mt, 32));
        if (lane < 16) Mx[wq][wd][lane] = mt;
        __syncthreads();                       // #1: Mx ready; V/K loads drained

        const float mfull = fmaxf(mt, Mx[wq][wd ^ 1][lr]);
        const float m_new = (mfull > m_run + 8.f) ? mfull : m_run;  // defer-max
        const float p0 = __expf(s[0] - m_new), p1 = __expf(s[1] - m_new);
        const float p2 = __expf(s[2] - m_new), p3 = __expf(s[3] - m_new);
        float ts = p0 + p1 + p2 + p3;
        ts += __shfl_xor(ts, 16);
        ts += __shfl_xor(ts, 32);
        if (lane < 16) Tx[wq][wd][lane] = ts;
        Pw[wq][lr * 20 + wd * 8 + g * 2 + 0] = pk2(p0, p1);
        Pw[wq][lr * 20 + wd * 8 + g * 2 + 1] = pk2(p2, p3);
        __syncthreads();                       // #2: Tx + P ready

        const float tsf = ts + Tx[wq][wd ^ 1][lr];
        if (__any(m_new != m_run)) {
            const float alpha = __expf(m_run - m_new);
            #pragma unroll
            for (int i = 0; i < 16; i++) {
                acc[i][0] *= alpha; acc[i][1] *= alpha;
                acc[i][2] *= alpha; acc[i][3] *= alpha;
            }
            l_run *= alpha;
        }
        l_run += tsf;
        m_run = m_new;

        // PV: P B-operand; V A-operand (half prefetched, half loaded here)
        bf16x8 pf;
        {
            union { unsigned int u[4]; bf16x8 v; } cv;
            #pragma unroll
            for (int j = 0; j < 4; j++) cv.u[j] = Pw[wq][lr * 20 + g * 4 + j];
            pf = cv.v;
        }
        bf16x8 vf2[8];
        #pragma unroll
        for (int d16 = 0; d16 < 8; d16++)
            vf2[d16] = *(const bf16x8*)&Vg[(size_t)((d16 + 8) * 16 + lr) * NPOS + kv0 + g * 8];
        #pragma unroll
        for (int d16 = 0; d16 < 8; d16++)
            acc[d16] = __builtin_amdgcn_mfma_f32_16x16x32_bf16(vf[d16], pf, acc[d16], 0, 0, 0);
        #pragma unroll
        for (int d16 = 0; d16 < 8; d16++)
            acc[d16 + 8] = __builtin_amdgcn_mfma_f32_16x16x32_bf16(vf2[d16], pf, acc[d16 + 8], 0, 0, 0);
    }

    // epilogue
    const float inv = 1.f / l_run;
    bf16* Og = O + ((size_t)b * NPOS + qt * QT + wq * 16 + lr) * CDIM + wd * 256;
    #pragma unroll
    for (int d16 = 0; d16 < 16; d16++) {
        bf16x4 o;
        o[0] = (bf16)(acc[d16][0] * inv); o[1] = (bf16)(acc[d16][1] * inv);
        o[2] = (bf16)(acc[d16][2] * inv); o[3] = (bf16)(acc[d16][3] * inv);
        *(bf16x4*)(Og + d16 * 16 + g * 4) = o;
    }
}

// ---------------- proj GEMM + bias + residual (f32 out) ----------------
__global__ __launch_bounds__(256) void gemm_proj(
    const bf16* __restrict__ A, const bf16* __restrict__ Bw,
    const float* __restrict__ bias, float* __restrict__ Cp,
    const float* __restrict__ resid)
{
    __shared__ __align__(16) bf16 lsa[BM * BK];
    __shared__ __align__(16) bf16 lsb[BN * BK];
    const int bid = blockIdx.x;
    const int xcd = bid & 7;
    const int local = bid >> 3;               // 0..63
    const int colT = local & 3;
    const int rowT = (xcd << 4) + (local >> 2);
    const int bm = rowT * BM;
    const int bn = colT * BN;
    const int t = threadIdx.x;
    const int lane = t & 63;
    const int wid = t >> 6;
    const int wr = (wid >> 1) * 64;
    const int wc = (wid & 1) * 64;
    const int lr = lane & 15;
    const int ks = lane >> 4;
    const int r0 = t >> 2, c0 = (t & 3) * 8;
    const int r1 = (t + 256) >> 2, c1 = ((t + 256) & 3) * 8;

    f32x4 acc[4][4] = {};
    for (int k0 = 0; k0 < CDIM; k0 += BK) {
        gload16(&A[(size_t)(bm + r0) * CDIM + k0 + c0], &lsa[t * 8]);
        gload16(&A[(size_t)(bm + r1) * CDIM + k0 + c1], &lsa[(t + 256) * 8]);
        gload16(&Bw[(size_t)(bn + r0) * CDIM + k0 + c0], &lsb[t * 8]);
        gload16(&Bw[(size_t)(bn + r1) * CDIM + k0 + c1], &lsb[(t + 256) * 8]);
        __syncthreads();
        bf16x8 af[4], bfr[4];
        #pragma unroll
        for (int m = 0; m < 4; m++)
            af[m] = *(const bf16x8*)&lsa[(wr + m * 16 + lr) * BK + ks * 8];
        #pragma unroll
        for (int n = 0; n < 4; n++)
            bfr[n] = *(const bf16x8*)&lsb[(wc + n * 16 + lr) * BK + ks * 8];
        #pragma unroll
        for (int m = 0; m < 4; m++)
            #pragma unroll
            for (int n = 0; n < 4; n++)
                acc[m][n] = __builtin_amdgcn_mfma_f32_16x16x32_bf16(af[m], bfr[n], acc[m][n], 0, 0, 0);
        __syncthreads();
    }
    #pragma unroll
    for (int m = 0; m < 4; m++) {
        #pragma unroll
        for (int n = 0; n < 4; n++) {
            const int row0 = bm + wr + m * 16 + ks * 4;
            const int col  = bn + wc + n * 16 + lr;
            const float bvl = bias[col];
            #pragma unroll
            for (int r = 0; r < 4; r++) {
                const size_t idx = (size_t)(row0 + r) * CDIM + col;
                Cp[idx] = acc[m][n][r] + bvl + resid[idx];
            }
        }
    }
}

// ---------------- launch ----------------
extern "C" void kernel_launch(void* const* d_in, const int* in_sizes, int n_in,
                              void* d_out, int out_size, void* d_ws, size_t ws_size,
                              hipStream_t stream) {
    const float* x     = (const float*)d_in[0];
    const float* gamma = (const float*)d_in[1];
    const float* beta  = (const float*)d_in[2];
    const float* wq    = (const float*)d_in[3];
    const float* bq    = (const float*)d_in[4];
    const float* wk    = (const float*)d_in[5];
    const float* bk    = (const float*)d_in[6];
    const float* wv    = (const float*)d_in[7];
    const float* bv    = (const float*)d_in[8];
    const float* wp    = (const float*)d_in[9];
    const float* bp    = (const float*)d_in[10];

    char* ws = (char*)d_ws;
    bf16* wt = (bf16*)(ws + OFF_WT);
    bf16* xn = (bf16*)(ws + OFF_XN);
    bf16* Q  = (bf16*)(ws + OFF_Q);
    bf16* Km = (bf16*)(ws + OFF_K);
    bf16* Vt = (bf16*)(ws + OFF_VT);
    bf16* O  = (bf16*)(ws + OFF_O);

    transpose_cast<<<dim3(16, 16, 4), 256, 0, stream>>>(wq, wk, wv, wp, wt);
    groupnorm_kernel<<<dim3(512), 256, 0, stream>>>(x, gamma, beta, xn);

    const float qscale = 0.04419417382415922f;  // 512^-0.5 folded into Q
    gemm_qkv<<<dim3(1536), 256, 0, stream>>>(
        xn, wt, bq, bk, bv, qscale, Q, Km, Vt);

    flash_attn<<<dim3(256), 512, 0, stream>>>(Q, Km, Vt, O);

    gemm_proj<<<dim3(512), 256, 0, stream>>>(
        O, wt + (size_t)3 * WELEMS, bp, (float*)d_out, x);
}